// Round 1
// 444.909 us; speedup vs baseline: 1.0538x; 1.0538x over previous
//
#include <hip/hip_runtime.h>
#include <math.h>

// Deblocking filter, fused vertical+horizontal, fully-coalesced float4 version.
// H=W=8192, BS=8, ALPHA=0.1, BETA=0.05 (fixed by reference setup).
//
// R2 theory: the 8x8-tile version (466-468 us) issued every load/store as
// 16B-per-lane at 32B stride (50% density per VMEM instruction) on BOTH the
// 300MB read stream and the 270MB write stream; the harness's own fill
// kernels hit 6.3 TB/s in the same capture, so the chip has 5x headroom.
// Here each thread owns ONE float4 (4 cols) x 9 rows of an 8-row tile:
// lane i accesses base + i*16 -> every wave load/store is a dense 1KiB
// transaction. Vertical-filter neighbors (2 floats outside the quad,
// alternating side by lane parity) come from an 8B float2 that L1-hits the
// line the adjacent lane just loaded. Math is bit-identical to the reference.

static constexpr int W = 8192;
static constexpr int H = 8192;
#define ALPHA 0.1f
#define BETA  0.05f

__device__ __forceinline__ bool dmask(float p1, float p0, float q0, float q1) {
    // exact float32 semantics, matches numpy (single sub, fabs, strict <)
    return (fabsf(p0 - q0) < ALPHA) && (fabsf(p1 - p0) < BETA) && (fabsf(q1 - q0) < BETA);
}
// filtered p0 (numpy op order: ((2*p1 + p0) + q0) + 2, then /4 — exact)
__device__ __forceinline__ float filt_p(float p1, float p0, float q0, float q1) {
    float v = (((2.0f * p1 + p0) + q0) + 2.0f) * 0.25f;
    return dmask(p1, p0, q0, q1) ? v : p0;
}
__device__ __forceinline__ float filt_q(float p1, float p0, float q0, float q1) {
    float v = (((2.0f * q1 + q0) + p0) + 2.0f) * 0.25f;
    return dmask(p1, p0, q0, q1) ? v : q0;
}

struct V4 { float v[4]; };

// stage1 (vertical pass) for aligned cols [c0, c0+3] of `row`.
// c0 % 8 == 0 ("even quad", cols ?0..3 mod 8): filtered col is c0 (q-side),
//   needs row[c0-2], row[c0-1] — skipped at c0 == 0 (no boundary at col 0).
// c0 % 8 == 4 ("odd quad", cols ?4..7 mod 8): filtered col is c0+3 (p-side),
//   needs row[c0+4], row[c0+5] — skipped when c0+4 == W (last boundary is 8184).
__device__ __forceinline__ V4 stage1_4(const float* __restrict__ row, int c0) {
    const float4 a = *reinterpret_cast<const float4*>(row + c0);
    V4 r;
    r.v[0] = a.x; r.v[1] = a.y; r.v[2] = a.z; r.v[3] = a.w;
    if ((c0 & 4) == 0) {
        if (c0 != 0) {
            const float2 pm = *reinterpret_cast<const float2*>(row + c0 - 2); // 8B aligned
            r.v[0] = filt_q(pm.x, pm.y, a.x, a.y);
        }
    } else {
        if (c0 + 4 != W) {
            const float2 qn = *reinterpret_cast<const float2*>(row + c0 + 4);
            r.v[3] = filt_p(a.z, a.w, qn.x, qn.y);
        }
    }
    return r;
}

__device__ __forceinline__ void store4(float* __restrict__ p, const V4& s) {
    *reinterpret_cast<float4*>(p) = make_float4(s.v[0], s.v[1], s.v[2], s.v[3]);
}

__global__ __launch_bounds__(256)
void deblock_f4(const float* __restrict__ in, float* __restrict__ out) {
    const int c0 = (blockIdx.x * 256 + threadIdx.x) * 4; // 4 cols/thread, dense
    const int k  = blockIdx.y;                           // tile: rows 8k+1..8k+8
    const size_t base = (size_t)(8 * k) * W;

    // rows 8k+1..8k+6: pass-through (vertical filter only); keep s1 of row 8k+6
    V4 s6;
    #pragma unroll
    for (int r = 1; r <= 6; ++r) {
        V4 s = stage1_4(in + base + (size_t)r * W, c0);
        if (r == 6) s6 = s;
        store4(out + base + (size_t)r * W + c0, s);
    }

    if (k != H / 8 - 1) {
        // boundary row i = 8k+8 (in 8..8184): out[i-1]=filt_p, out[i]=filt_q,
        // both from stage1 rows 8k+6..8k+9 (all still original-input-derived)
        V4 s7 = stage1_4(in + base + (size_t)7 * W, c0);
        V4 s8 = stage1_4(in + base + (size_t)8 * W, c0);
        V4 s9 = stage1_4(in + base + (size_t)9 * W, c0);
        V4 rp, rq;
        #pragma unroll
        for (int c = 0; c < 4; ++c) {
            rp.v[c] = filt_p(s6.v[c], s7.v[c], s8.v[c], s9.v[c]);
            rq.v[c] = filt_q(s6.v[c], s7.v[c], s8.v[c], s9.v[c]);
        }
        store4(out + base + (size_t)7 * W + c0, rp);
        store4(out + base + (size_t)8 * W + c0, rq);
    } else {
        // last tile: row 8191 is pass-through (no boundary at row 8192);
        // row 0 (pass-through, untouched by h-pass) handled here too
        V4 s7 = stage1_4(in + base + (size_t)7 * W, c0);
        store4(out + base + (size_t)7 * W + c0, s7);
        V4 s0 = stage1_4(in, c0);
        store4(out + c0, s0);
    }
}

extern "C" void kernel_launch(void* const* d_in, const int* in_sizes, int n_in,
                              void* d_out, int out_size, void* d_ws, size_t ws_size,
                              hipStream_t stream) {
    const float* frame = (const float*)d_in[0];
    float* out = (float*)d_out;
    dim3 block(256, 1, 1);
    // x: 2048 float4-groups / 256 threads = 8 blocks; y: 1024 row-tiles
    dim3 grid(W / 4 / 256, H / 8, 1);
    deblock_f4<<<grid, block, 0, stream>>>(frame, out);
}